// Round 1
// 758.799 us; speedup vs baseline: 1.2766x; 1.2766x over previous
//
#include <hip/hip_runtime.h>

// ---------------------------------------------------------------------------
// CriticNetwork: GRU over T=256 steps (B=1024, H=256, F=65) + 2-critic MLP.
// Kernel 1 (gru_kernel): persistent, 256 blocks x 512 thr (8 waves, 2/SIMD).
//   Wh held as bf16 MFMA B-fragments in REGISTERS. Input projection fused
//   (every 4 steps, M = 4 batch x 4 time).
//   THIS ROUND: real batch rows remapped to M-rows {0,4,8,12} so reg r=0 of
//   EVERY lane is a real row (batch = kg) -> gate math 4x smaller, no exec
//   mask on h-writes. h buffer = 4 real rows + 1 shared zero row, stride 544
//   (2-way max bank pattern; fake lanes broadcast-read the zero row).
// Kernel 2 (head_kernel): twin critic MLPs, 32 blocks, MFMA. (unchanged)
// ---------------------------------------------------------------------------

#define TSEQ 256
#define DPDIM 64

typedef float f32x4 __attribute__((ext_vector_type(4)));
typedef __bf16 bf16x8 __attribute__((ext_vector_type(8)));
typedef unsigned short ushort8 __attribute__((ext_vector_type(8)));

static __device__ __forceinline__ unsigned short f2bf(float f) {
  unsigned u = __builtin_bit_cast(unsigned, f);
  return (unsigned short)((u + 0x7fffu + ((u >> 16) & 1u)) >> 16);  // RNE
}
static __device__ __forceinline__ float bf2f(unsigned short h) {
  return __builtin_bit_cast(float, ((unsigned)h) << 16);
}
static __device__ __forceinline__ float sigm(float x) {
  return __builtin_amdgcn_rcpf(1.f + __expf(-x));
}
static __device__ __forceinline__ float tanh_fast(float p) {
  float q = __expf(-2.f * fabsf(p));
  float t = (1.f - q) * __builtin_amdgcn_rcpf(1.f + q);
  return __builtin_bit_cast(float, __builtin_bit_cast(unsigned, t) |
                                   (__builtin_bit_cast(unsigned, p) & 0x80000000u));
}

// ---- GRU kernel LDS layout (bytes) ----
#define OFF_WIT 0         // Wi transposed bf16 [768 n][72 k-stride] = 768*144
#define OFF_XP  110592    // xp bf16 [768 col][16 row] stride 32B = 768*32
#define OFF_H0  135168    // h buf0 bf16 [4 real rows + 1 zero row][272] stride 544B
#define OFF_H1  137888    // h buf1 (same shape)
#define OFF_BI  140608    // bi f32 [768]
#define OFF_W64 143680    // Wi row 64 (weight channel) f32 [768]
#define OFF_BHN 146752    // bhn f32 [256]
#define LDS_GRU 147776

#define HSTRIDE 544       // h row stride in bytes (2-way max bank pattern)

__global__ __launch_bounds__(512, 2) void gru_kernel(
    const float* __restrict__ particles, const float* __restrict__ weights,
    const float* __restrict__ Wi, const float* __restrict__ bi,
    const float* __restrict__ Wh, const float* __restrict__ bhn,
    unsigned short* __restrict__ hT)
{
  extern __shared__ char smem[];
  const int tid  = threadIdx.x;
  const int lane = tid & 63;
  const int w    = tid >> 6;      // wave id 0..7
  const int l15  = lane & 15;
  const int kg   = lane >> 4;     // k-group 0..3
  const int b0   = blockIdx.x * 4;

  // ---------------- prologue ----------------
  // Wi rows 0..63 -> LDS transposed bf16 (B-operand friendly: k contiguous per n)
  for (int idx = tid; idx < 64 * 768; idx += 512) {
    int k = idx / 768, n = idx - k * 768;
    *(unsigned short*)(smem + OFF_WIT + n * 144 + k * 2) = f2bf(Wi[idx]);
  }
  for (int idx = tid; idx < 768; idx += 512) {
    *(float*)(smem + OFF_BI  + idx * 4) = bi[idx];
    *(float*)(smem + OFF_W64 + idx * 4) = Wi[64 * 768 + idx];
  }
  if (tid < 256) *(float*)(smem + OFF_BHN + tid * 4) = bhn[tid];
  // zero both h buffers (incl. the shared zero row 4, never written again)
  for (int idx = tid; idx < (2 * 5 * HSTRIDE) / 4; idx += 512)
    ((unsigned*)(smem + OFF_H0))[idx] = 0u;

  // Wh -> register B-fragments. Wave w owns N-tiles {w+8j}, j=0..5:
  //   j=0,1 -> r-gate tiles (hidden tiles w, w+8); j=2,3 -> z; j=4,5 -> n.
  bf16x8 whb[6][8];
  #pragma unroll
  for (int j = 0; j < 6; ++j) {
    const int tile = w + 8 * j;
    const float* wp = Wh + (size_t)(kg * 8) * 768 + tile * 16 + l15;
    #pragma unroll
    for (int ks = 0; ks < 8; ++ks) {
      ushort8 tmp;
      #pragma unroll
      for (int e = 0; e < 8; ++e)
        tmp[e] = f2bf(wp[(size_t)(ks * 32 + e) * 768]);
      whb[j][ks] = __builtin_bit_cast(bf16x8, tmp);
    }
  }
  __syncthreads();

  // A-fragment source for the recurrence: M-row l15 is real iff l15%4==0
  // (batch = l15>>2, stored at h row l15>>2); all other lanes read the
  // shared zero row 4 (same-address broadcast within kg groups -> ~free).
  const unsigned arow = ((l15 & 3) == 0)
                      ? (unsigned)((l15 >> 2) * HSTRIDE + kg * 16)
                      : (unsigned)(4 * HSTRIDE + kg * 16);

  f32x4 acc[6];
  const f32x4 fzero = {0.f, 0.f, 0.f, 0.f};

  for (int g = 0; g < 64; ++g) {
    const int t0 = g * 4;

    // ---------------- xp phase: project inputs for t0..t0+3 ----------------
    // M-row m = 4*t' + b  (t' = time-in-group, b = batch-in-block)
    float wv[4];
    #pragma unroll
    for (int r = 0; r < 4; ++r) {
      int row = kg * 4 + r;
      wv[r] = weights[(b0 + (row & 3)) * TSEQ + t0 + (row >> 2)];
    }
    #pragma unroll
    for (int j = 0; j < 6; ++j) acc[j] = fzero;
    #pragma unroll
    for (int ks = 0; ks < 2; ++ks) {
      const float* pp = particles +
          ((size_t)(b0 + (l15 & 3)) * TSEQ + (t0 + (l15 >> 2))) * DPDIM + ks * 32 + kg * 8;
      f32x4 pa = *(const f32x4*)pp;
      f32x4 pb = *(const f32x4*)(pp + 4);
      ushort8 tmp;
      tmp[0] = f2bf(pa[0]); tmp[1] = f2bf(pa[1]); tmp[2] = f2bf(pa[2]); tmp[3] = f2bf(pa[3]);
      tmp[4] = f2bf(pb[0]); tmp[5] = f2bf(pb[1]); tmp[6] = f2bf(pb[2]); tmp[7] = f2bf(pb[3]);
      bf16x8 af = __builtin_bit_cast(bf16x8, tmp);
      #pragma unroll
      for (int j = 0; j < 6; ++j) {
        const int n = (w + 8 * j) * 16 + l15;
        bf16x8 bf = *(const bf16x8*)(smem + OFF_WIT + n * 144 + ks * 64 + kg * 16);
        acc[j] = __builtin_amdgcn_mfma_f32_16x16x32_bf16(af, bf, acc[j], 0, 0, 0);
      }
    }
    #pragma unroll
    for (int j = 0; j < 6; ++j) {
      const int col  = (w + 8 * j) * 16 + l15;
      const float biv = *(const float*)(smem + OFF_BI  + col * 4);
      const float w64 = *(const float*)(smem + OFF_W64 + col * 4);
      float v0 = acc[j][0] + biv + wv[0] * w64;
      float v1 = acc[j][1] + biv + wv[1] * w64;
      float v2 = acc[j][2] + biv + wv[2] * w64;
      float v3 = acc[j][3] + biv + wv[3] * w64;
      uint2 val;
      val.x = (unsigned)f2bf(v0) | ((unsigned)f2bf(v1) << 16);
      val.y = (unsigned)f2bf(v2) | ((unsigned)f2bf(v3) << 16);
      // xp cols are wave-private (writer == only reader) -> no barrier needed
      *(uint2*)(smem + OFF_XP + col * 32 + kg * 8) = val;
    }

    // ---------------- 4 GRU steps ----------------
    #pragma unroll
    for (int tt = 0; tt < 4; ++tt) {
      const int t     = t0 + tt;
      const int rboff = (t & 1) ? OFF_H1 : OFF_H0;   // read buffer
      const int wboff = (t & 1) ? OFF_H0 : OFF_H1;   // write buffer
      #pragma unroll
      for (int j = 0; j < 6; ++j) acc[j] = fzero;
      const char* hb = smem + rboff;
      #pragma unroll
      for (int ks = 0; ks < 8; ++ks) {
        bf16x8 af = *(const bf16x8*)(hb + arow + ks * 64);
        #pragma unroll
        for (int j = 0; j < 6; ++j)
          acc[j] = __builtin_amdgcn_mfma_f32_16x16x32_bf16(af, whb[j][ks], acc[j], 0, 0, 0);
      }
      // Gates: reg 0 of each acc is M-row 4*kg = batch kg -> every lane
      // computes exactly one real (batch, hidden-col) pair per p. No mask.
      const int m = 4 * tt + kg;   // xp row for (batch kg, time tt)
      #pragma unroll
      for (int p = 0; p < 2; ++p) {
        const int hcol = (w + 8 * p) * 16 + l15;
        const float bhv = *(const float*)(smem + OFF_BHN + hcol * 4);
        float xr = bf2f(*(const unsigned short*)(smem + OFF_XP + (hcol      ) * 32 + m * 2));
        float xz = bf2f(*(const unsigned short*)(smem + OFF_XP + (hcol + 256) * 32 + m * 2));
        float xn = bf2f(*(const unsigned short*)(smem + OFF_XP + (hcol + 512) * 32 + m * 2));
        float rr = sigm(xr + acc[p][0]);
        float zz = sigm(xz + acc[2 + p][0]);
        float nn = tanh_fast(xn + rr * (acc[4 + p][0] + bhv));
        float ho = bf2f(*(const unsigned short*)(smem + rboff + kg * HSTRIDE + hcol * 2));
        *(unsigned short*)(smem + wboff + kg * HSTRIDE + hcol * 2) =
            f2bf(nn + zz * (ho - nn));
      }
      __syncthreads();
    }
  }

  // final h is in buf0 (t=255 wrote OFF_H0); real rows are 0..3 (batch)
  for (int idx = tid; idx < 1024; idx += 512) {
    int b = idx >> 8, k = idx & 255;
    hT[(b0 + b) * 256 + k] = *(const unsigned short*)(smem + OFF_H0 + b * HSTRIDE + k * 2);
  }
}

// ---- Head kernel LDS layout ----
#define HOFF_XA 0         // x tile bf16 [64][296] stride 592B
#define HOFF_B  37888     // B stage bf16 [256 n][40 k] stride 80B
#define HOFF_H1 58368     // h1 bf16 [64][264] stride 528B
#define HOFF_H2 92160
#define HOFF_B1 125952
#define HOFF_B2 126976
#define HOFF_W3 128000
#define LDS_HEAD 129024

__global__ __launch_bounds__(256, 2) void head_kernel(
    const unsigned short* __restrict__ hT, const float* __restrict__ action,
    const float* __restrict__ time_idx, const float* __restrict__ W1,
    const float* __restrict__ b1, const float* __restrict__ W2,
    const float* __restrict__ b2, const float* __restrict__ W3,
    const float* __restrict__ b3, float* __restrict__ out)
{
  extern __shared__ char smem[];
  const int tid  = threadIdx.x;
  const int lane = tid & 63;
  const int w    = tid >> 6;
  const int l15  = lane & 15;
  const int kg   = lane >> 4;
  const int c    = blockIdx.x & 1;
  const int rt   = blockIdx.x >> 1;
  const int r0   = rt * 64;

  if (tid < 256) {
    *(float*)(smem + HOFF_B1 + tid * 4) = b1[c * 256 + tid];
    *(float*)(smem + HOFF_B2 + tid * 4) = b2[c * 256 + tid];
    *(float*)(smem + HOFF_W3 + tid * 4) = W3[c * 256 + tid];
  }
  // x = [h | action | t/100 | zero-pad to 288]
  for (int idx = tid; idx < 64 * 296; idx += 256) {
    int row = idx / 296, k = idx - row * 296;
    unsigned short v;
    if (k < 256)       v = hT[(r0 + row) * 256 + k];
    else if (k < 264)  v = f2bf(action[(r0 + row) * 8 + (k - 256)]);
    else if (k == 264) v = f2bf(time_idx[r0 + row] * 0.01f);
    else               v = 0;
    *(unsigned short*)(smem + HOFF_XA + row * 592 + k * 2) = v;
  }

  f32x4 acc[4][4];
  const f32x4 fzero = {0.f, 0.f, 0.f, 0.f};

  // ---- layer 1: h1 = relu(x @ W1[c] + b1[c]), K = 265 padded to 288 ----
  #pragma unroll
  for (int mt = 0; mt < 4; ++mt)
    #pragma unroll
    for (int i = 0; i < 4; ++i) acc[mt][i] = fzero;
  for (int ks = 0; ks < 9; ++ks) {
    for (int idx = tid; idx < 32 * 256; idx += 256) {
      int kk = idx >> 8, n = idx & 255;
      int kglob = ks * 32 + kk;
      float v = (kglob < 265) ? W1[((size_t)c * 265 + kglob) * 256 + n] : 0.f;
      *(unsigned short*)(smem + HOFF_B + n * 80 + kk * 2) = f2bf(v);
    }
    __syncthreads();
    bf16x8 bfr[4];
    #pragma unroll
    for (int i = 0; i < 4; ++i)
      bfr[i] = *(const bf16x8*)(smem + HOFF_B + ((w * 4 + i) * 16 + l15) * 80 + kg * 16);
    #pragma unroll
    for (int mt = 0; mt < 4; ++mt) {
      bf16x8 af = *(const bf16x8*)(smem + HOFF_XA + (mt * 16 + l15) * 592 + ks * 64 + kg * 16);
      #pragma unroll
      for (int i = 0; i < 4; ++i)
        acc[mt][i] = __builtin_amdgcn_mfma_f32_16x16x32_bf16(af, bfr[i], acc[mt][i], 0, 0, 0);
    }
    __syncthreads();
  }
  #pragma unroll
  for (int mt = 0; mt < 4; ++mt)
    #pragma unroll
    for (int i = 0; i < 4; ++i) {
      int col = (w * 4 + i) * 16 + l15;
      float bv = *(const float*)(smem + HOFF_B1 + col * 4);
      #pragma unroll
      for (int r = 0; r < 4; ++r) {
        float v = acc[mt][i][r] + bv; v = v > 0.f ? v : 0.f;
        *(unsigned short*)(smem + HOFF_H1 + (mt * 16 + kg * 4 + r) * 528 + col * 2) = f2bf(v);
      }
    }
  __syncthreads();

  // ---- layer 2: h2 = relu(h1 @ W2[c] + b2[c]), K = 256 ----
  #pragma unroll
  for (int mt = 0; mt < 4; ++mt)
    #pragma unroll
    for (int i = 0; i < 4; ++i) acc[mt][i] = fzero;
  for (int ks = 0; ks < 8; ++ks) {
    for (int idx = tid; idx < 32 * 256; idx += 256) {
      int kk = idx >> 8, n = idx & 255;
      float v = W2[((size_t)c * 256 + ks * 32 + kk) * 256 + n];
      *(unsigned short*)(smem + HOFF_B + n * 80 + kk * 2) = f2bf(v);
    }
    __syncthreads();
    bf16x8 bfr[4];
    #pragma unroll
    for (int i = 0; i < 4; ++i)
      bfr[i] = *(const bf16x8*)(smem + HOFF_B + ((w * 4 + i) * 16 + l15) * 80 + kg * 16);
    #pragma unroll
    for (int mt = 0; mt < 4; ++mt) {
      bf16x8 af = *(const bf16x8*)(smem + HOFF_H1 + (mt * 16 + l15) * 528 + ks * 64 + kg * 16);
      #pragma unroll
      for (int i = 0; i < 4; ++i)
        acc[mt][i] = __builtin_amdgcn_mfma_f32_16x16x32_bf16(af, bfr[i], acc[mt][i], 0, 0, 0);
    }
    __syncthreads();
  }
  #pragma unroll
  for (int mt = 0; mt < 4; ++mt)
    #pragma unroll
    for (int i = 0; i < 4; ++i) {
      int col = (w * 4 + i) * 16 + l15;
      float bv = *(const float*)(smem + HOFF_B2 + col * 4);
      #pragma unroll
      for (int r = 0; r < 4; ++r) {
        float v = acc[mt][i][r] + bv; v = v > 0.f ? v : 0.f;
        *(unsigned short*)(smem + HOFF_H2 + (mt * 16 + kg * 4 + r) * 528 + col * 2) = f2bf(v);
      }
    }
  __syncthreads();

  // ---- layer 3: v = h2 @ W3[c] + b3[c] (VALU dot, 4 threads/row) ----
  {
    int row = tid >> 2, q = tid & 3;
    float s = 0.f;
    #pragma unroll
    for (int i = 0; i < 16; ++i) {
      uint2 hh = *(const uint2*)(smem + HOFF_H2 + row * 528 + (q * 64 + i * 4) * 2);
      const float* w3p = (const float*)(smem + HOFF_W3) + q * 64 + i * 4;
      s += bf2f((unsigned short)hh.x)         * w3p[0];
      s += bf2f((unsigned short)(hh.x >> 16)) * w3p[1];
      s += bf2f((unsigned short)hh.y)         * w3p[2];
      s += bf2f((unsigned short)(hh.y >> 16)) * w3p[3];
    }
    s += __shfl_xor(s, 1);
    s += __shfl_xor(s, 2);
    if (q == 0) out[(r0 + row) * 2 + c] = s + b3[c];
  }
}

extern "C" void kernel_launch(void* const* d_in, const int* in_sizes, int n_in,
                              void* d_out, int out_size, void* d_ws, size_t ws_size,
                              hipStream_t stream) {
  const float* particles = (const float*)d_in[0];
  const float* weights   = (const float*)d_in[1];
  const float* action    = (const float*)d_in[2];
  const float* time_idx  = (const float*)d_in[3];
  const float* Wi        = (const float*)d_in[4];
  const float* bi        = (const float*)d_in[5];
  const float* Wh        = (const float*)d_in[6];
  const float* bhn       = (const float*)d_in[7];
  const float* W1        = (const float*)d_in[8];
  const float* b1        = (const float*)d_in[9];
  const float* W2        = (const float*)d_in[10];
  const float* b2        = (const float*)d_in[11];
  const float* W3        = (const float*)d_in[12];
  const float* b3        = (const float*)d_in[13];
  unsigned short* hT = (unsigned short*)d_ws;   // [1024][256] bf16
  float* out = (float*)d_out;

  (void)hipFuncSetAttribute((const void*)gru_kernel,
                            hipFuncAttributeMaxDynamicSharedMemorySize, LDS_GRU);
  (void)hipFuncSetAttribute((const void*)head_kernel,
                            hipFuncAttributeMaxDynamicSharedMemorySize, LDS_HEAD);

  hipLaunchKernelGGL(gru_kernel, dim3(256), dim3(512), LDS_GRU, stream,
                     particles, weights, Wi, bi, Wh, bhn, hT);
  hipLaunchKernelGGL(head_kernel, dim3(32), dim3(256), LDS_HEAD, stream,
                     hT, action, time_idx, W1, b1, W2, b2, W3, b3, out);
}